// Round 10
// baseline (9834.926 us; speedup 1.0000x reference)
//
#include <hip/hip_runtime.h>
#include <hip/hip_fp8.h>
#include <stdint.h>

typedef __attribute__((ext_vector_type(8))) short short8v;
typedef __attribute__((ext_vector_type(4))) float f32x4;
typedef _Float16 h2 __attribute__((ext_vector_type(2)));

// ---------- helpers ----------
__device__ __forceinline__ uint16_t f2bf(float f){
  union{float f; uint32_t i;}v; v.f = f;
  uint32_t x = v.i;
  x += 0x7fffu + ((x>>16)&1u);
  return (uint16_t)(x>>16);
}
__device__ __forceinline__ uint8_t f2fp8(float f){
  return __builtin_bit_cast(uint8_t, __hip_fp8_e4m3(f));
}
__device__ __forceinline__ float fp82f(uint8_t b){
  return (float)__builtin_bit_cast(__hip_fp8_e4m3, b);
}
__device__ __forceinline__ h2 as_h2(uint32_t u){ return __builtin_bit_cast(h2, u); }
__device__ __forceinline__ float dot2(h2 a, h2 b, float c){
#if __has_builtin(__builtin_amdgcn_fdot2)
  return __builtin_amdgcn_fdot2(a, b, c, false);
#else
  return c + (float)a[0]*(float)b[0] + (float)a[1]*(float)b[1];
#endif
}

// ---------- prep: zero y, copy hidden -> h0, convert weights to fp16 ----------
__global__ void prep_kernel(const float* __restrict__ hidden,
                            const float* __restrict__ Wq, const float* __restrict__ Wo,
                            const float* __restrict__ w_ih, const float* __restrict__ w_hh,
                            float* __restrict__ y, float* __restrict__ h0,
                            _Float16* __restrict__ wq_h, _Float16* __restrict__ wo_h,
                            _Float16* __restrict__ wih_h, _Float16* __restrict__ whh_h){
  int idx = blockIdx.x*blockDim.x + threadIdx.x;
  int n = gridDim.x*blockDim.x;
  for (int i=idx; i<4096; i+=n) y[i] = 0.f;
  for (int i=idx; i<32768; i+=n) h0[i] = hidden[i];
  for (int i=idx; i<262144; i+=n) wq_h[i] = (_Float16)Wq[i];
  for (int i=idx; i<262144; i+=n) wo_h[i] = (_Float16)Wo[i];
  for (int i=idx; i<1536*544; i+=n){
    int j = i/544, c = i - j*544;
    wih_h[i] = (c<513) ? (_Float16)w_ih[(size_t)j*513 + c] : (_Float16)0.f;
  }
  for (int i=idx; i<1536*512; i+=n) whh_h[i] = (_Float16)w_hh[i];
}

// ---------- enc echo (runs AFTER the loop; K/V live in this region during the loop) ----------
__global__ void copy_enc_kernel(const float4* __restrict__ src, float4* __restrict__ dst, int n4){
  int idx = blockIdx.x*blockDim.x + threadIdx.x;
  int stride = gridDim.x*blockDim.x;
  for (int i=idx; i<n4; i+=stride) dst[i] = src[i];
}

// ---------- K/V projection via bf16 MFMA (unchanged from R4): fp8 store ----------
__global__ __launch_bounds__(256) void kv_build_kernel(
    const float* __restrict__ enc, const float* __restrict__ Wk, const float* __restrict__ Wv,
    uint8_t* __restrict__ Kf, uint8_t* __restrict__ Vf)
{
  __shared__ uint16_t As[128][40];
  __shared__ uint16_t Bs[128][40];
  const int s0 = blockIdx.x*128;
  const int d0 = blockIdx.y*128;
  const int z  = blockIdx.z;
  const int b  = z>>1;
  const float* __restrict__ W = (z&1) ? Wv : Wk;
  uint8_t* __restrict__ On    = (z&1) ? Vf : Kf;
  const int tid = threadIdx.x;
  const int wv = tid>>6, lane = tid&63;
  const int r = tid>>1, hh = (tid&1)*16;
  const float* encb = enc + (size_t)b*1024*512;

  f32x4 acc[2][8];
  #pragma unroll
  for (int i=0;i<2;++i)
    #pragma unroll
    for (int j=0;j<8;++j) acc[i][j] = (f32x4){0.f,0.f,0.f,0.f};

  const int fr = lane&15, kq = (lane>>4)*8;

  for (int k0=0;k0<512;k0+=32){
    const float4* sa = (const float4*)(encb + (size_t)(s0+r)*512 + k0 + hh);
    const float4* sb = (const float4*)(W    + (size_t)(d0+r)*512 + k0 + hh);
    float4 va[4], vb[4];
    #pragma unroll
    for (int q=0;q<4;++q){ va[q]=sa[q]; vb[q]=sb[q]; }
    __syncthreads();
    uint16_t* pa = &As[r][hh];
    uint16_t* pb = &Bs[r][hh];
    #pragma unroll
    for (int q=0;q<4;++q){
      pa[4*q+0]=f2bf(va[q].x); pa[4*q+1]=f2bf(va[q].y); pa[4*q+2]=f2bf(va[q].z); pa[4*q+3]=f2bf(va[q].w);
      pb[4*q+0]=f2bf(vb[q].x); pb[4*q+1]=f2bf(vb[q].y); pb[4*q+2]=f2bf(vb[q].z); pb[4*q+3]=f2bf(vb[q].w);
    }
    __syncthreads();
    short8v af[2], bfr[8];
    af[0] = *(const short8v*)&As[wv*32 +      fr][kq];
    af[1] = *(const short8v*)&As[wv*32 + 16 + fr][kq];
    #pragma unroll
    for (int n2=0;n2<8;++n2) bfr[n2] = *(const short8v*)&Bs[n2*16 + fr][kq];
    #pragma unroll
    for (int mi=0;mi<2;++mi)
      #pragma unroll
      for (int n2=0;n2<8;++n2)
        acc[mi][n2] = __builtin_amdgcn_mfma_f32_16x16x32_bf16(af[mi], bfr[n2], acc[mi][n2], 0,0,0);
  }
  const int rq = (lane>>4)*4;
  #pragma unroll
  for (int mi=0;mi<2;++mi){
    #pragma unroll
    for (int reg=0; reg<4; ++reg){
      int s = s0 + wv*32 + mi*16 + rq + reg;
      #pragma unroll
      for (int n2=0;n2<8;++n2){
        int d = d0 + n2*16 + fr;
        int head = d>>8, dh = d&255;
        On[(((size_t)b*2+head)*1024 + s)*256 + dh] = f2fp8(acc[mi][n2][reg]);
      }
    }
  }
}

// ---------- fused decoder step: one block per batch element, 1024 threads ----------
__global__ __launch_bounds__(1024) void step_kernel(
    const uint8_t* __restrict__ Kf, const uint8_t* __restrict__ Vf,
    const float* __restrict__ h_in, float* __restrict__ h_out,
    const _Float16* __restrict__ wq_h, const _Float16* __restrict__ wo_h,
    const _Float16* __restrict__ wih_h, const _Float16* __restrict__ whh_h,
    const float* __restrict__ b_ih, const float* __restrict__ b_hh,
    const float* __restrict__ Wd, const float* __restrict__ bd,
    const float* __restrict__ X, float* __restrict__ y, int t)
{
  const int b = blockIdx.x, tid = threadIdx.x;
  const int lane = tid&63, wid = tid>>6;
  __shared__ float h_s[512];
  __shared__ __align__(16) h2 hh_s[256];
  __shared__ float q_s[512];
  __shared__ float p_s[2][1024];
  __shared__ float red[40];
  __shared__ float cpa[8][512];
  __shared__ float ctx_f[512];
  __shared__ __align__(16) h2 ctx_h[256];
  __shared__ __align__(16) _Float16 xin_half[544];

  // P0: load h
  if (tid<256){
    float2 hv = ((const float2*)(h_in + (size_t)b*512))[tid];
    h_s[2*tid]=hv.x; h_s[2*tid+1]=hv.y;
    hh_s[tid] = (h2){(_Float16)hv.x, (_Float16)hv.y};
  }
  __syncthreads();

  // P1: q = (h @ Wq^T) * 1/sqrt(DH); 2 threads per output
  {
    int o = tid>>1, hf = tid&1;
    const uint4* wr = ((const uint4*)(wq_h + (size_t)o*512)) + hf*32;
    const uint4* hp = ((const uint4*)hh_s) + hf*32;
    float s=0.f;
    #pragma unroll 8
    for (int i=0;i<32;++i){
      uint4 w = wr[i], hv = hp[i];
      s = dot2(as_h2(w.x), as_h2(hv.x), s);
      s = dot2(as_h2(w.y), as_h2(hv.y), s);
      s = dot2(as_h2(w.z), as_h2(hv.z), s);
      s = dot2(as_h2(w.w), as_h2(hv.w), s);
    }
    s += __shfl_xor(s,1);
    if (hf==0) q_s[o] = s*0.0625f;
  }
  __syncthreads();

  // P2: scores for both heads, full S=1024; 4 lanes per row, 8 passes
  {
    int qd = tid&3, rb2 = tid>>2;
    #pragma unroll
    for (int p=0;p<8;++p){
      int r2 = p*256 + rb2;
      int head = r2>>10, s2 = r2&1023;
      const uint4* Kr = (const uint4*)(Kf + (((size_t)b*2+head)*1024 + s2)*256);
      float s=0.f;
      #pragma unroll
      for (int u=0;u<4;++u){
        uint4 v = Kr[qd+4*u];
        const float* qq = q_s + head*256 + (qd+4*u)*16;
        uint32_t w;
        w = v.x;
        s = fmaf(fp82f(w&255), qq[0], s);  s = fmaf(fp82f((w>>8)&255), qq[1], s);
        s = fmaf(fp82f((w>>16)&255), qq[2], s); s = fmaf(fp82f(w>>24), qq[3], s);
        w = v.y;
        s = fmaf(fp82f(w&255), qq[4], s);  s = fmaf(fp82f((w>>8)&255), qq[5], s);
        s = fmaf(fp82f((w>>16)&255), qq[6], s); s = fmaf(fp82f(w>>24), qq[7], s);
        w = v.z;
        s = fmaf(fp82f(w&255), qq[8], s);  s = fmaf(fp82f((w>>8)&255), qq[9], s);
        s = fmaf(fp82f((w>>16)&255), qq[10], s); s = fmaf(fp82f(w>>24), qq[11], s);
        w = v.w;
        s = fmaf(fp82f(w&255), qq[12], s); s = fmaf(fp82f((w>>8)&255), qq[13], s);
        s = fmaf(fp82f((w>>16)&255), qq[14], s); s = fmaf(fp82f(w>>24), qq[15], s);
      }
      s += __shfl_xor(s,1); s += __shfl_xor(s,2);
      if (qd==0) p_s[head][s2] = s;
    }
  }
  __syncthreads();

  // P3: exact softmax per head (block-wide, both heads in parallel)
  float a0 = p_s[0][tid], a1 = p_s[1][tid];
  {
    float v0=a0, v1=a1;
    #pragma unroll
    for (int o=32;o;o>>=1){ v0=fmaxf(v0,__shfl_xor(v0,o)); v1=fmaxf(v1,__shfl_xor(v1,o)); }
    if (lane==0){ red[wid]=v0; red[16+wid]=v1; }
  }
  __syncthreads();
  if (tid==0){
    float m0=red[0], m1=red[16];
    for (int i=1;i<16;++i){ m0=fmaxf(m0,red[i]); m1=fmaxf(m1,red[16+i]); }
    red[32]=m0; red[33]=m1;
  }
  __syncthreads();
  float e0 = __expf(a0-red[32]), e1 = __expf(a1-red[33]);
  p_s[0][tid]=e0; p_s[1][tid]=e1;
  {
    float v0=e0, v1=e1;
    #pragma unroll
    for (int o=32;o;o>>=1){ v0+=__shfl_xor(v0,o); v1+=__shfl_xor(v1,o); }
    if (lane==0){ red[wid]=v0; red[16+wid]=v1; }
  }
  __syncthreads();
  if (tid==0){
    float l0=0.f,l1=0.f;
    for (int i=0;i<16;++i){ l0+=red[i]; l1+=red[16+i]; }
    red[36]=1.f/l0; red[37]=1.f/l1;
  }
  __syncthreads();

  // P4: ctx = P @ V; 128 output-units x 8 s-slices
  {
    int u = tid&127, sh = tid>>7;
    int head = u>>6, d4 = (u&63)*4;
    const uint8_t* Vb = Vf + (((size_t)b*2+head)*1024 + sh*128)*256 + d4;
    const float* pp = &p_s[head][sh*128];
    float c0=0,c1=0,c2=0,c3=0;
    #pragma unroll 4
    for (int s2=0;s2<128;++s2){
      float pw = pp[s2];
      uint32_t v = *(const uint32_t*)(Vb + (size_t)s2*256);
      c0 = fmaf(pw, fp82f(v&255), c0);
      c1 = fmaf(pw, fp82f((v>>8)&255), c1);
      c2 = fmaf(pw, fp82f((v>>16)&255), c2);
      c3 = fmaf(pw, fp82f(v>>24), c3);
    }
    int ob = head*256 + d4;
    cpa[sh][ob]=c0; cpa[sh][ob+1]=c1; cpa[sh][ob+2]=c2; cpa[sh][ob+3]=c3;
  }
  __syncthreads();
  if (tid<512){
    float s=0.f;
    #pragma unroll
    for (int sh=0;sh<8;++sh) s += cpa[sh][tid];
    ctx_f[tid] = s * red[36 + (tid>>8)];
  }
  __syncthreads();
  if (tid<256) ctx_h[tid] = (h2){(_Float16)ctx_f[2*tid], (_Float16)ctx_f[2*tid+1]};
  __syncthreads();

  // P5: xin = ctx @ Wo^T (+ x_t, pad); 2 threads per output
  {
    int j = tid>>1, hf = tid&1;
    const uint4* wr = ((const uint4*)(wo_h + (size_t)j*512)) + hf*32;
    const uint4* cp4 = ((const uint4*)ctx_h) + hf*32;
    float s=0.f;
    #pragma unroll 8
    for (int i=0;i<32;++i){
      uint4 w = wr[i], cv = cp4[i];
      s = dot2(as_h2(w.x), as_h2(cv.x), s);
      s = dot2(as_h2(w.y), as_h2(cv.y), s);
      s = dot2(as_h2(w.z), as_h2(cv.z), s);
      s = dot2(as_h2(w.w), as_h2(cv.w), s);
    }
    s += __shfl_xor(s,1);
    if (hf==0) xin_half[j] = (_Float16)s;
  }
  if (tid>=512 && tid<544) xin_half[tid] = (tid==512) ? (_Float16)X[(size_t)b*64+t] : (_Float16)0.f;
  __syncthreads();

  // P6: GRU; 2 threads (k-slices) per j
  {
    int ks = tid&1, j = tid>>1;
    float g6[6];
    #pragma unroll
    for (int g=0; g<3; ++g){
      const uint4* wr = ((const uint4*)(wih_h + (size_t)(g*512+j)*544)) + ks*34;
      const uint4* xp = ((const uint4*)xin_half) + ks*34;
      float s=0.f;
      #pragma unroll 2
      for (int i=0;i<34;++i){
        uint4 w = wr[i], xv = xp[i];
        s = dot2(as_h2(w.x), as_h2(xv.x), s);
        s = dot2(as_h2(w.y), as_h2(xv.y), s);
        s = dot2(as_h2(w.z), as_h2(xv.z), s);
        s = dot2(as_h2(w.w), as_h2(xv.w), s);
      }
      g6[g]=s;
      const uint4* wh = ((const uint4*)(whh_h + (size_t)(g*512+j)*512)) + ks*32;
      const uint4* hp = ((const uint4*)hh_s) + ks*32;
      float s2=0.f;
      #pragma unroll 2
      for (int i=0;i<32;++i){
        uint4 w = wh[i], hv = hp[i];
        s2 = dot2(as_h2(w.x), as_h2(hv.x), s2);
        s2 = dot2(as_h2(w.y), as_h2(hv.y), s2);
        s2 = dot2(as_h2(w.z), as_h2(hv.z), s2);
        s2 = dot2(as_h2(w.w), as_h2(hv.w), s2);
      }
      g6[3+g]=s2;
    }
    #pragma unroll
    for (int i2=0;i2<6;++i2) g6[i2] += __shfl_xor(g6[i2],1);
    float part = 0.f;
    if (ks==0){
      float gi0=g6[0]+b_ih[j], gi1=g6[1]+b_ih[512+j], gi2=g6[2]+b_ih[1024+j];
      float gh0=g6[3]+b_hh[j], gh1=g6[4]+b_hh[512+j], gh2=g6[5]+b_hh[1024+j];
      float r = 1.f/(1.f+__expf(-(gi0+gh0)));
      float z = 1.f/(1.f+__expf(-(gi1+gh1)));
      float n = tanhf(gi2 + r*gh2);
      float hn = (1.f-z)*n + z*h_s[j];
      h_out[(size_t)b*512+j] = hn;
      part = hn*Wd[j];
    }
    #pragma unroll
    for (int o=32;o;o>>=1) part += __shfl_xor(part,o);
    if (lane==0) red[wid] = part;
  }
  __syncthreads();
  if (tid==0){
    float s = bd[0];
    for (int i=0;i<16;++i) s += red[i];
    y[(size_t)b*64+t] = s;
  }
}

// ---------- final h copy ----------
__global__ void fin_kernel(const float* __restrict__ hfin, float* __restrict__ dst){
  int i = blockIdx.x*blockDim.x + threadIdx.x;
  if (i < 32768) dst[i] = hfin[i];
}

extern "C" void kernel_launch(void* const* d_in, const int* in_sizes, int n_in,
                              void* d_out, int out_size, void* d_ws, size_t ws_size,
                              hipStream_t stream)
{
  const float* X    = (const float*)d_in[0];
  const float* enc  = (const float*)d_in[1];
  const float* hid  = (const float*)d_in[2];
  const float* Wq   = (const float*)d_in[3];
  const float* Wk   = (const float*)d_in[4];
  const float* Wv   = (const float*)d_in[5];
  const float* Wo   = (const float*)d_in[6];
  const float* w_ih = (const float*)d_in[7];
  const float* w_hh = (const float*)d_in[8];
  const float* b_ih = (const float*)d_in[9];
  const float* b_hh = (const float*)d_in[10];
  const float* Wd   = (const float*)d_in[11];
  const float* bd   = (const float*)d_in[12];
  float* out = (float*)d_out;

  // K/V (fp8 e4m3) live in the enc-echo region of d_out during the loop;
  // enc echo is written AFTER the loop.
  uint8_t* Kf = (uint8_t*)(out + 4096);
  uint8_t* Vf = Kf + 33554432;

  char* ws = (char*)d_ws;
  float*     h0    = (float*)(ws + 0);           // 131072 B
  float*     h1    = (float*)(ws + 131072);      // 131072 B
  _Float16*  wq_h  = (_Float16*)(ws + 262144);   // 524288 B  [512][512]
  _Float16*  wo_h  = (_Float16*)(ws + 786432);   // 524288 B  [512][512]
  _Float16*  wih_h = (_Float16*)(ws + 1310720);  // 1671168 B [1536][544]
  _Float16*  whh_h = (_Float16*)(ws + 2981888);  // 1572864 B [1536][512]

  prep_kernel<<<dim3(512), dim3(256), 0, stream>>>(hid, Wq, Wo, w_ih, w_hh, out, h0,
                                                   wq_h, wo_h, wih_h, whh_h);
  kv_build_kernel<<<dim3(8,4,128), dim3(256), 0, stream>>>(enc, Wk, Wv, Kf, Vf);

  float* hb[2] = {h0, h1};
  for (int t=0; t<64; ++t){
    const float* hi = hb[t&1];
    float* ho = hb[1-(t&1)];
    step_kernel<<<dim3(64), dim3(1024), 0, stream>>>(Kf, Vf, hi, ho,
                                                     wq_h, wo_h, wih_h, whh_h,
                                                     b_ih, b_hh, Wd, bd, X, out, t);
  }
  // overwrite K/V region with the enc echo
  copy_enc_kernel<<<dim3(4096), dim3(256), 0, stream>>>((const float4*)enc, (float4*)(out + 4096), 8388608);
  fin_kernel<<<dim3(128), dim3(256), 0, stream>>>(h0, out + 4096 + 33554432);
}